// Round 20
// baseline (11530.111 us; speedup 1.0000x reference)
//
#include <hip/hip_runtime.h>
#include <stdint.h>

#define HID 1024
#define NGATE 4096
#define BATCH 256
#define TENC 128
#define VOCAB 1024
#define NOUT 125
#define TDEC 141
#define MAXTHINK 16
#define STOPCLS 1023

typedef __attribute__((ext_vector_type(8))) short short8;
typedef __attribute__((ext_vector_type(4))) float f32x4;

#define WPLE ((size_t)NGATE*1024)
#define VPLE ((size_t)VOCAB*1024)
#define MFMA_B __builtin_amdgcn_mfma_f32_16x16x32_bf16

#define I_CLAIM 0
#define I_FLAGS 64
#define I_GEN   4224
#define I_ANY   4288
#define I_PRED  4608

// light barrier: waits LDS ops only, leaves global loads (vmcnt) in flight.
#define LBAR() do { asm volatile("s_waitcnt lgkmcnt(0)" ::: "memory"); \
                    __builtin_amdgcn_s_barrier(); } while(0)

// ---------------- threefry2x32 (exact JAX partitionable semantics) ----------------
__device__ __forceinline__ uint32_t rotl32(uint32_t v, int r){ return (v<<r)|(v>>(32-r)); }

__device__ __forceinline__ void tf2x32(uint32_t k0, uint32_t k1, uint32_t x0, uint32_t x1,
                                       uint32_t& o0, uint32_t& o1)
{
  uint32_t k2 = k0 ^ k1 ^ 0x1BD11BDAu;
  x0 += k0; x1 += k1;
#define R4(a,b,cc,d) x0+=x1;x1=rotl32(x1,a);x1^=x0; x0+=x1;x1=rotl32(x1,b);x1^=x0; \
                     x0+=x1;x1=rotl32(x1,cc);x1^=x0; x0+=x1;x1=rotl32(x1,d);x1^=x0;
  R4(13,15,26,6)  x0+=k1; x1+=k2+1u;
  R4(17,29,16,24) x0+=k2; x1+=k0+2u;
  R4(13,15,26,6)  x0+=k0; x1+=k1+3u;
  R4(17,29,16,24) x0+=k1; x1+=k2+4u;
  R4(13,15,26,6)  x0+=k2; x1+=k0+5u;
#undef R4
  o0 = x0; o1 = x1;
}

__device__ __forceinline__ uint32_t jax_bits(uint32_t fk0, uint32_t fk1, uint32_t i)
{
  uint32_t o0, o1;
  tf2x32(fk0, fk1, 0u, i, o0, o1);
  return o0 ^ o1;
}

__device__ __forceinline__ float sigm(float x){ return 0.5f + 0.5f*tanhf(0.5f*x); }

__device__ __forceinline__ ushort bf16rn(float v){
  uint32_t u = __float_as_uint(v);
  uint32_t r = (u + 0x7fffu + ((u>>16)&1u)) >> 16;
  return (ushort)r;
}
__device__ __forceinline__ float bf16tof(ushort s){ return __uint_as_float(((uint32_t)s)<<16); }

// ---------------- coherent (fabric) helpers: GLOBAL addrspace -> global_* (vmcnt only) ----
typedef unsigned long long __attribute__((address_space(1))) gu64_t;
typedef int                __attribute__((address_space(1))) gi32_t;
typedef unsigned short     __attribute__((address_space(1))) gu16_t;

__device__ __forceinline__ uint64_t cld8(const ushort* p){
  return __hip_atomic_load((const gu64_t*)(uintptr_t)p, __ATOMIC_RELAXED, __HIP_MEMORY_SCOPE_AGENT);
}
__device__ __forceinline__ void cst8(ushort* p, uint64_t v){
  __hip_atomic_store((gu64_t*)(uintptr_t)p, v, __ATOMIC_RELAXED, __HIP_MEMORY_SCOPE_AGENT);
}
__device__ __forceinline__ float cld4f(const float* p){
  int v = __hip_atomic_load((const gi32_t*)(uintptr_t)p, __ATOMIC_RELAXED, __HIP_MEMORY_SCOPE_AGENT);
  return __int_as_float(v);
}
__device__ __forceinline__ void cst4f(float* p, float x){
  __hip_atomic_store((gi32_t*)(uintptr_t)p, __float_as_int(x), __ATOMIC_RELAXED, __HIP_MEMORY_SCOPE_AGENT);
}
__device__ __forceinline__ int cld4i(const int* p){
  return __hip_atomic_load((const gi32_t*)(uintptr_t)p, __ATOMIC_RELAXED, __HIP_MEMORY_SCOPE_AGENT);
}
__device__ __forceinline__ void cst4i(int* p, int v){
  __hip_atomic_store((gi32_t*)(uintptr_t)p, v, __ATOMIC_RELAXED, __HIP_MEMORY_SCOPE_AGENT);
}
__device__ __forceinline__ ushort cld2(const ushort* p){
  return __hip_atomic_load((const gu16_t*)(uintptr_t)p, __ATOMIC_RELAXED, __HIP_MEMORY_SCOPE_AGENT);
}
__device__ __forceinline__ void cst2(ushort* p, ushort v){
  __hip_atomic_store((gu16_t*)(uintptr_t)p, v, __ATOMIC_RELAXED, __HIP_MEMORY_SCOPE_AGENT);
}

typedef ushort GatesLds[2][3][32][40];   // A staging: 32 rows x 32 elems, +pad

// ---------------- grid barrier: pure control ----------------
__device__ __forceinline__ void gbar(int* flags, int* gen, int e, int rk, int tid)
{
  __syncthreads();     // drains vmcnt -> all coherent stores reached fabric
  if (tid == 0)
    __hip_atomic_store((gi32_t*)(uintptr_t)&flags[rk*16], e, __ATOMIC_RELAXED, __HIP_MEMORY_SCOPE_AGENT);
  if (rk == 0){
    if (tid < 256){
      while (cld4i(&flags[tid*16]) < e)
        __builtin_amdgcn_s_sleep(1);
    }
    __syncthreads();
    if (tid == 0)
      __hip_atomic_store((gi32_t*)(uintptr_t)gen, e, __ATOMIC_RELAXED, __HIP_MEMORY_SCOPE_AGENT);
  } else if (tid == 0){
    while (cld4i(gen) < e)
      __builtin_amdgcn_s_sleep(1);
  }
  __syncthreads();
}

// ---------------- prep ----------------
__global__ __launch_bounds__(256) void prep_kernel(
    const float* __restrict__ b_ih, const float* __restrict__ b_hh,
    const float* __restrict__ x, const int* __restrict__ lengths,
    float* __restrict__ bsum, int* __restrict__ ints,
    ushort* __restrict__ h3i, ushort* __restrict__ cur3i,
    ushort* __restrict__ h3p0, ushort* __restrict__ curp0)
{
  int idx = blockIdx.x*256 + threadIdx.x;           // b*1024 + k
  if (idx < NGATE) bsum[idx] = b_ih[idx] + b_hh[idx];
  if (idx < 8)   ints[I_CLAIM + idx] = 0;
  if (idx < 256) ints[I_FLAGS + idx*16] = 0;
  if (idx == 0)  ints[I_GEN] = 0;
  if (idx < TDEC+1) ints[I_ANY + idx] = (idx==0) ? 1 : 0;
  *(unsigned long long*)(h3i + (size_t)idx*4) = 0ull;
  h3p0[idx] = 0;
  int b = idx >> 10, k = idx & (HID-1);
  int L = lengths[b];
  float v = x[((size_t)b*TENC + (size_t)(L-1))*HID + k];
  ushort p0 = bf16rn(v); v -= bf16tof(p0);
  ushort p1 = bf16rn(v); v -= bf16tof(p1);
  ushort p2 = bf16rn(v);
  *(unsigned long long*)(cur3i + (size_t)idx*4) =
      (uint64_t)p0 | ((uint64_t)p1<<16) | ((uint64_t)p2<<32);
  curp0[idx] = p0;
}

// ---------------- weight pre-split into frag-ordered bf16 planes ----------------
__global__ __launch_bounds__(256) void splitw_kernel(
    const float* __restrict__ W, ushort* __restrict__ Wf, int N)
{
  int idx = blockIdx.x*256 + threadIdx.x;   // n*128 + kc
  int n = idx >> 7, kc = idx & 127;
  float v[8];
  *(float4*)&v[0] = *(const float4*)(W + (size_t)n*1024 + kc*8);
  *(float4*)&v[4] = *(const float4*)(W + (size_t)n*1024 + kc*8 + 4);
  size_t base = ((size_t)(n>>4)*128 + kc)*128 + (n&15)*8;
  #pragma unroll
  for (int p=0;p<3;p++){
    ushort o[8];
    #pragma unroll
    for (int e=0;e<8;e++){ ushort pp = bf16rn(v[e]); v[e] -= bf16tof(pp); o[e] = pp; }
    *(uint4*)(Wf + (size_t)p*N*1024 + base) = *(uint4*)o;
  }
}

// ================= phase helpers =================

// gates + LSTM cell. MODE0 encoder: K=2048 fused [x_t inline-split | h3]·[Wih|Whh], mask.
// MODE1 decode: K=2048 [cur3|h3]·[Wih|Whh]. MODE2: K=1024 h·Whh + W_ih column gather.
// PL3: interleaved A records; PL1: compact plane-0 A.
template<int PL, int MODE>
__device__ void gates_do(
    const ushort* __restrict__ A0i, const ushort* __restrict__ A1i,
    const ushort* __restrict__ A0c, const ushort* __restrict__ A1c,
    const ushort* __restrict__ Wih, const ushort* __restrict__ Whh,
    const float* __restrict__ Wihf, const int* __restrict__ pred,
    const float* __restrict__ xsrc,
    int t, const int* len2, const float (*bs2)[4],
    float* creg, ushort* __restrict__ h3newi, ushort* __restrict__ h3p0new,
    GatesLds& As, char* ep_mem,
    int xcc, int bb, int kg, int tid)
{
  constexpr int KT = (MODE==2) ? 32 : 64;
  float (*ep)[32][33] = reinterpret_cast<float(*)[32][33]>(ep_mem);
  int lane = tid & 63, w = tid >> 6;
  int fr = lane & 15, q = lane >> 4;
  int arow = tid >> 4, apos = tid & 15;
  int bf = w & 1, kf = (w>>1) & 1, gh = w >> 2;

  size_t off[2];
  #pragma unroll
  for (int g2=0; g2<2; g2++)
    off[g2] = ((size_t)((2*gh+g2)*64 + xcc*8 + kg*2 + kf)*128 + q)*128 + fr*8;

  f32x4 acc[2] = {};

#define LOADSA(sv, kc) { \
  int kcl = ((kc) < KT) ? (kc) : 0; \
  int kl = kcl & 31; \
  if constexpr (PL==3){ \
    if (MODE==0 && kcl < 32){ \
      const float* xp = xsrc + ((size_t)(bb + arow)*TENC + t)*HID + kl*32 + apos*2; \
      float2 xv = *(const float2*)xp; \
      float v0 = xv.x; \
      ushort a0 = bf16rn(v0); v0 -= bf16tof(a0); \
      ushort a1 = bf16rn(v0); v0 -= bf16tof(a1); \
      ushort a2 = bf16rn(v0); \
      float v1 = xv.y; \
      ushort c0 = bf16rn(v1); v1 -= bf16tof(c0); \
      ushort c1 = bf16rn(v1); v1 -= bf16tof(c1); \
      ushort c2 = bf16rn(v1); \
      sv[0] = (uint64_t)a0 | ((uint64_t)a1<<16) | ((uint64_t)a2<<32); \
      sv[1] = (uint64_t)c0 | ((uint64_t)c1<<16) | ((uint64_t)c2<<32); \
    } else { \
      const ushort* ai = (MODE==1 && kcl < 32) ? A0i : A1i; \
      _Pragma("unroll") for (int j=0;j<2;j++) \
        sv[j] = cld8(ai + ((size_t)(bb + arow)*1024 + kl*32 + apos*2 + j)*4); \
    } \
  } else { \
    const ushort* ac = (MODE==1 && kcl < 32) ? A0c : A1c; \
    sv[0] = (uint64_t)(uint)cld4i((const int*)(ac + (size_t)(bb + arow)*1024 + kl*32 + apos*2)); \
  } }

#define STAGE(buf, sv) { \
  if constexpr (PL==3){ \
    _Pragma("unroll") for (int p=0;p<3;p++){ \
      uint lo = (uint)((sv[0] >> (16*p)) & 0xffffu) | ((uint)((sv[1] >> (16*p)) & 0xffffu) << 16); \
      *(uint*)&As[buf][p][arow][apos*2] = lo; } \
  } else { \
    *(uint*)&As[buf][0][arow][apos*2] = (uint)sv[0]; \
  } }

#define LOADB(dst, kc) { \
  int kcl = ((kc) < KT) ? (kc) : 0; \
  const ushort* wsel = (MODE!=2 && kcl < 32) ? Wih : Whh; \
  int kl = kcl & 31; \
  _Pragma("unroll") for (int p=0;p<PL;p++) \
  _Pragma("unroll") for (int g2=0; g2<2; g2++) \
    dst[p][g2] = *(const short8*)(wsel + (size_t)p*WPLE + off[g2] + (size_t)kl*512); }

#define READA(af, buf) { _Pragma("unroll") for (int p=0;p<PL;p++) af[p] = *(const short8*)&As[buf][p][bf*16 + fr][q*8]; }

#define DOMFMA(aa, bf_) { _Pragma("unroll") for (int g2=0; g2<2; g2++){ \
  if constexpr (PL==3){ \
    acc[g2] = MFMA_B(aa[2], bf_[0][g2], acc[g2], 0,0,0); \
    acc[g2] = MFMA_B(aa[1], bf_[1][g2], acc[g2], 0,0,0); \
    acc[g2] = MFMA_B(aa[0], bf_[2][g2], acc[g2], 0,0,0); \
    acc[g2] = MFMA_B(aa[1], bf_[0][g2], acc[g2], 0,0,0); \
    acc[g2] = MFMA_B(aa[0], bf_[1][g2], acc[g2], 0,0,0); \
    acc[g2] = MFMA_B(aa[0], bf_[0][g2], acc[g2], 0,0,0); \
  } else { \
    acc[g2] = MFMA_B(aa[0], bf_[0][g2], acc[g2], 0,0,0); \
  } } }

  uint64_t sv0[2], sv1[2], sv2[2], sv3[2];
  short8 bq0[PL][2], bq1[PL][2], afc[PL], afn[PL];
  LOADSA(sv0, 0); LOADSA(sv1, 1); LOADSA(sv2, 2); LOADSA(sv3, 3);
  LOADB(bq0, 0);
  STAGE(0, sv0); LBAR();
  READA(afc, 0);
  LOADSA(sv0, 4);
  for (int kc = 0; kc < KT; kc += 4){
    STAGE(1, sv1); LBAR();
    READA(afn, 1);
    LOADB(bq1, kc+1); LOADSA(sv1, kc+5);
    DOMFMA(afc, bq0);

    STAGE(0, sv2); LBAR();
    READA(afc, 0);
    LOADB(bq0, kc+2); LOADSA(sv2, kc+6);
    DOMFMA(afn, bq1);

    STAGE(1, sv3); LBAR();
    READA(afn, 1);
    LOADB(bq1, kc+3); LOADSA(sv3, kc+7);
    DOMFMA(afc, bq0);

    STAGE(0, sv0); LBAR();
    READA(afc, 0);
    LOADB(bq0, kc+4); LOADSA(sv0, kc+8);
    DOMFMA(afn, bq1);
  }
#undef LOADSA
#undef STAGE
#undef LOADB
#undef READA
#undef DOMFMA

  // exchange accumulators through LDS, then per-element cell epilogue
  __syncthreads();
  #pragma unroll
  for (int g2=0; g2<2; g2++)
    #pragma unroll
    for (int r=0;r<4;r++)
      ep[2*gh+g2][bf*16 + q*4 + r][kf*16 + fr] = acc[g2][r];
  __syncthreads();

  #pragma unroll
  for (int e2=0; e2<2; e2++){
    int e = tid + e2*512;
    int b_loc = e >> 5, k_loc = e & 31;
    int b = bb + b_loc;
    int kkloc = kg*32 + k_loc;
    int kkg = xcc*128 + kkloc;
    size_t eidx = (size_t)b*1024 + kkg;
    if (MODE==0 && t >= len2[e2]){
      cst8(h3newi + eidx*4, cld8(A1i + eidx*4));   // keep old h (c untouched)
      cst2(h3p0new + eidx, cld2(A1c + eidx));
      continue;
    }
    float gi = ep[0][b_loc][k_loc], gf = ep[1][b_loc][k_loc];
    float gg2v = ep[2][b_loc][k_loc], go = ep[3][b_loc][k_loc];
    if (MODE==2){
      int pp = cld4i(pred + b);
      gi   += Wihf[(size_t)(        kkg)*1024 + pp];
      gf   += Wihf[(size_t)(1024 + kkg)*1024 + pp];
      gg2v += Wihf[(size_t)(2048 + kkg)*1024 + pp];
      go   += Wihf[(size_t)(3072 + kkg)*1024 + pp];
    }
    gi += bs2[e2][0]; gf += bs2[e2][1]; gg2v += bs2[e2][2]; go += bs2[e2][3];
    float cn = sigm(gf)*creg[e2] + sigm(gi)*tanhf(gg2v);
    float hn = sigm(go)*tanhf(cn);
    creg[e2] = cn;
    float v = hn;
    ushort p0 = bf16rn(v); v -= bf16tof(p0);
    cst2(h3p0new + eidx, p0);
    if constexpr (PL==3){
      ushort p1 = bf16rn(v); v -= bf16tof(p1);
      ushort p2 = bf16rn(v);
      cst8(h3newi + eidx*4, (uint64_t)p0 | ((uint64_t)p1<<16) | ((uint64_t)p2<<32));
    }
  }
}

// FC: PL3 reads interleaved h3i; PL1 reads compact h3c plane-0.
template<int PL>
__device__ void fc_do(
    const ushort* __restrict__ h3i, const ushort* __restrict__ h3c,
    const ushort* __restrict__ wfc,
    float* __restrict__ logits, GatesLds& As,
    int xcc, int bb, int vg, int tid)
{
  int lane = tid & 63, w = tid >> 6;
  int fr = lane & 15, q = lane >> 4;
  int arow = tid >> 4, apos = tid & 15;
  int bf = w & 1, vf = (w>>1) & 1;
  bool act = (w < 4);
  size_t off = ((size_t)(xcc*8 + vg*2 + vf)*128 + q)*128 + fr*8;
  f32x4 acc = {};

#define FLOADSA(sv, kc) { \
  int kcl = ((kc) < 32) ? (kc) : 0; \
  if constexpr (PL==3){ \
    _Pragma("unroll") for (int j=0;j<2;j++) \
      sv[j] = cld8(h3i + ((size_t)(bb + arow)*1024 + kcl*32 + apos*2 + j)*4); \
  } else { \
    sv[0] = (uint64_t)(uint)cld4i((const int*)(h3c + (size_t)(bb + arow)*1024 + kcl*32 + apos*2)); \
  } }

#define FSTAGE(buf, sv) { \
  if constexpr (PL==3){ \
    _Pragma("unroll") for (int p=0;p<3;p++){ \
      uint lo = (uint)((sv[0] >> (16*p)) & 0xffffu) | ((uint)((sv[1] >> (16*p)) & 0xffffu) << 16); \
      *(uint*)&As[buf][p][arow][apos*2] = lo; } \
  } else { \
    *(uint*)&As[buf][0][arow][apos*2] = (uint)sv[0]; \
  } }

#define FLOADB(dst, kc) { if (act){ \
  int kcl = ((kc) < 32) ? (kc) : 0; \
  _Pragma("unroll") for (int p=0;p<PL;p++) \
    dst[p] = *(const short8*)(wfc + (size_t)p*VPLE + off + (size_t)kcl*512); } }

#define FMM(aa, bf_) { if (act){ \
  if constexpr (PL==3){ \
    acc = MFMA_B(aa[2], bf_[0], acc, 0,0,0); \
    acc = MFMA_B(aa[1], bf_[1], acc, 0,0,0); \
    acc = MFMA_B(aa[0], bf_[2], acc, 0,0,0); \
    acc = MFMA_B(aa[1], bf_[0], acc, 0,0,0); \
    acc = MFMA_B(aa[0], bf_[1], acc, 0,0,0); \
    acc = MFMA_B(aa[0], bf_[0], acc, 0,0,0); \
  } else { \
    acc = MFMA_B(aa[0], bf_[0], acc, 0,0,0); \
  } } }

#define FREADA(af, buf) { if (act){ _Pragma("unroll") for (int p=0;p<PL;p++) af[p] = *(const short8*)&As[buf][p][bf*16 + fr][q*8]; } }

  uint64_t sv0[2], sv1[2], sv2[2], sv3[2];
  short8 bq0[PL], bq1[PL], afc[PL], afn[PL];
  FLOADSA(sv0, 0); FLOADSA(sv1, 1); FLOADSA(sv2, 2); FLOADSA(sv3, 3);
  FLOADB(bq0, 0);
  FSTAGE(0, sv0); LBAR();
  FREADA(afc, 0);
  FLOADSA(sv0, 4);
  for (int kc = 0; kc < 32; kc += 4){
    FSTAGE(1, sv1); LBAR();
    FREADA(afn, 1);
    FLOADB(bq1, kc+1); FLOADSA(sv1, kc+5);
    FMM(afc, bq0);

    FSTAGE(0, sv2); LBAR();
    FREADA(afc, 0);
    FLOADB(bq0, kc+2); FLOADSA(sv2, kc+6);
    FMM(afn, bq1);

    FSTAGE(1, sv3); LBAR();
    FREADA(afn, 1);
    FLOADB(bq1, kc+3); FLOADSA(sv3, kc+7);
    FMM(afc, bq0);

    FSTAGE(0, sv0); LBAR();
    FREADA(afc, 0);
    FLOADB(bq0, kc+4); FLOADSA(sv0, kc+8);
    FMM(afn, bq1);
  }
#undef FLOADSA
#undef FSTAGE
#undef FLOADB
#undef FMM
#undef FREADA

  if (act){
    int v = xcc*128 + vg*32 + vf*16 + fr;
    #pragma unroll
    for (int r=0;r<4;r++)
      cst4f(logits + (size_t)(bb + bf*16 + q*4 + r)*1024 + v, acc[r]);
  }
}

// decide: one block per batch b (512 threads, 2 vocab each); state in registers
__device__ void decide_do(
    const float* __restrict__ logits, const float* __restrict__ b_fc, int t, int b,
    int* anyA, int* pred, float* __restrict__ out,
    ushort* __restrict__ cur3i, ushort* __restrict__ curp0,
    int& isth, int& tsteps, int& osteps,
    float* s_red, int* s_idx, int* s_misc, int tid)
{
  if (tid==0) s_misc[0] = cld4i(anyA + t);
  uint32_t fk0, fk1; tf2x32(0u, 42u, 0u, (uint32_t)t, fk0, fk1);
  float lg[2];
  float zb = -3.4e38f; int ib = 0;
  #pragma unroll
  for (int q2=0;q2<2;q2++){
    int v = tid + (q2<<9);
    uint32_t bits = jax_bits(fk0, fk1, (uint32_t)(b*VOCAB + v));
    float f = __uint_as_float((bits>>9) | 0x3F800000u) - 1.0f;
    const float TINY = 1.17549435e-38f;
    float u = fmaxf(TINY, f + TINY);
    float g = -logf(-logf(u));
    float l = cld4f(logits + (size_t)b*VOCAB + v) + b_fc[v];
    lg[q2] = l;
    float zz = l + g;
    if (zz > zb){ zb = zz; ib = v; }
  }
  s_red[tid] = zb; s_idx[tid] = ib;
  __syncthreads();
  for (int s2=256;s2>0;s2>>=1){
    if (tid < s2){
      float om = s_red[tid+s2]; int oi = s_idx[tid+s2];
      if (om > s_red[tid] || (om==s_red[tid] && oi < s_idx[tid])){ s_red[tid]=om; s_idx[tid]=oi; }
    }
    __syncthreads();
  }
  int predv = s_idx[0];
  int anyv  = s_misc[0];
  int outp = (!isth && osteps < NOUT) ? 1 : 0;
  int si = osteps < (NOUT-1) ? osteps : (NOUT-1);
  int nts = tsteps + (isth ? 1 : 0);
  int jf = (isth && ((predv==STOPCLS) || (nts >= MAXTHINK))) ? 1 : 0;
  int isnew = (isth && !jf) ? 1 : 0;
  if (tid==0){
    cst4i(pred + b, predv);
    if (isnew) __hip_atomic_fetch_or(&anyA[t+1], 1, __ATOMIC_RELAXED, __HIP_MEMORY_SCOPE_AGENT);
    if (t == TDEC-1) out[(size_t)BATCH*NOUT*(VOCAB-1) + b] = (float)nts;
  }
  osteps += outp; tsteps = nts; isth = isnew;
  #pragma unroll
  for (int q2=0;q2<2;q2++){
    int v = tid + (q2<<9);
    float l = lg[q2];
    float cv = anyv ? l : (v==predv ? 1.0f : 0.0f);
    if (t < MAXTHINK){
      float t2 = cv;
      ushort p0 = bf16rn(t2); t2 -= bf16tof(p0);
      ushort p1 = bf16rn(t2); t2 -= bf16tof(p1);
      ushort p2 = bf16rn(t2);
      cst8(cur3i + ((size_t)b*1024 + v)*4,
           (uint64_t)p0 | ((uint64_t)p1<<16) | ((uint64_t)p2<<32));
      cst2(curp0 + (size_t)b*1024 + v, p0);
    }
    if (outp && v < (VOCAB-1))
      out[((size_t)b*NOUT + si)*(VOCAB-1) + v] = l;
  }
}

// ================= persistent kernel =================
struct KP {
  const float *x, *W_ih, *b_fc, *bsum;
  const int *lengths;
  float *logits, *out;
  ushort *h3a, *h3b, *cur3, *wih3, *whh3, *wfc3;
  ushort *h3p0a, *h3p0b, *curp0;
  int *ints;
  int guard;
};

__global__ __launch_bounds__(512, 2) void persist(KP P)
{
  __shared__ __align__(16) char ep_mem[17408];   // gates epilogue exchange (4x32x33 f32)
  __shared__ __align__(16) GatesLds As;          // 15360 B
  __shared__ float s_red[512];
  __shared__ int s_idx[512];
  __shared__ int s_misc[16];
  __shared__ char lds_pad[49152];                // total > 80 KiB -> 1 block/CU
  if (P.guard){ ((volatile char*)lds_pad)[0] = 1; ((volatile char*)ep_mem)[0] = 1; }

  int tid = threadIdx.x;
  int xcc; asm("s_getreg_b32 %0, hwreg(HW_REG_XCC_ID)" : "=s"(xcc));
  xcc &= 7;
  if (tid == 0)
    s_misc[8] = __hip_atomic_fetch_add(&P.ints[I_CLAIM + xcc], 1, __ATOMIC_RELAXED, __HIP_MEMORY_SCOPE_AGENT);
  __syncthreads();
  int rank  = s_misc[8] & 31;                 // 32 blocks/XCD by 1-block/CU residency
  int rk256 = xcc*32 + rank;

  int bg = rank >> 2, kg = rank & 3;
  int bb = bg * 32;

  float bs2[2][4]; int len2[2]; float creg[2] = {0.f, 0.f};
  #pragma unroll
  for (int e2=0; e2<2; e2++){
    int e = tid + e2*512;
    int b_loc = e >> 5, k_loc = e & 31;
    int b = bb + b_loc;
    int kkg = xcc*128 + kg*32 + k_loc;
    #pragma unroll
    for (int g=0; g<4; g++) bs2[e2][g] = P.bsum[g*1024 + kkg];
    len2[e2] = P.lengths[b];
  }

  int* flags = P.ints + I_FLAGS;
  int* gen   = P.ints + I_GEN;
  int* anyA  = P.ints + I_ANY;
  int* pred  = P.ints + I_PRED;
  int epoch = 0;
  ushort* h3[2]   = { P.h3a,   P.h3b };
  ushort* h3p0[2] = { P.h3p0a, P.h3p0b };
  int hc = 0;
  int isth = 1, tsteps = 0, osteps = 0;

#define GBAR() gbar(flags, gen, ++epoch, rk256, tid)

  // ---- encoder: 128 steps, fused K=2048 [x_t | h] gates ----
  for (int t = 0; t < TENC; ++t){
    gates_do<3,0>(nullptr, h3[hc], nullptr, h3p0[hc], P.wih3, P.whh3, nullptr, nullptr, P.x,
                  t, len2, bs2, creg, h3[hc^1], h3p0[hc^1], As, ep_mem, xcc, bb, kg, tid);
    hc ^= 1;
    GBAR();
  }

  // ---- decode: 141 steps x { gates, fc, decide } ----
  for (int t = 0; t < TDEC; ++t){
    if (t < MAXTHINK)
      gates_do<3,1>(P.cur3, h3[hc], nullptr, nullptr, P.wih3, P.whh3, nullptr, nullptr, nullptr,
                    t, len2, bs2, creg, h3[hc^1], h3p0[hc^1], As, ep_mem, xcc, bb, kg, tid);
    else if (t == MAXTHINK)   // cur entering t=16 is LOGITS (any was true at t=15)
      gates_do<1,1>(nullptr, nullptr, P.curp0, h3p0[hc], P.wih3, P.whh3, nullptr, nullptr, nullptr,
                    t, len2, bs2, creg, h3[hc^1], h3p0[hc^1], As, ep_mem, xcc, bb, kg, tid);
    else                      // t>=17: cur exactly one-hot -> W_ih column gather
      gates_do<1,2>(nullptr, nullptr, nullptr, h3p0[hc], nullptr, P.whh3, P.W_ih, pred, nullptr,
                    t, len2, bs2, creg, h3[hc^1], h3p0[hc^1], As, ep_mem, xcc, bb, kg, tid);
    hc ^= 1;
    GBAR();
    if (t < MAXTHINK) fc_do<3>(h3[hc], nullptr, P.wfc3, P.logits, As, xcc, bb, kg, tid);
    else              fc_do<1>(nullptr, h3p0[hc], P.wfc3, P.logits, As, xcc, bb, kg, tid);
    GBAR();
    decide_do(P.logits, P.b_fc, t, rk256, anyA, pred, P.out, P.cur3, P.curp0,
              isth, tsteps, osteps, s_red, s_idx, s_misc, tid);
    GBAR();
  }
#undef GBAR
}

// ---------------- host ----------------
extern "C" void kernel_launch(void* const* d_in, const int* in_sizes, int n_in,
                              void* d_out, int out_size, void* d_ws, size_t ws_size,
                              hipStream_t stream)
{
  const float* x    = (const float*)d_in[0];
  const float* W_ih = (const float*)d_in[1];
  const float* W_hh = (const float*)d_in[2];
  const float* b_ih = (const float*)d_in[3];
  const float* b_hh = (const float*)d_in[4];
  const float* W_fc = (const float*)d_in[5];
  const float* b_fc = (const float*)d_in[6];
  const int*   lengths = (const int*)d_in[7];
  float* out = (float*)d_out;
  char* W = (char*)d_ws;

  constexpr size_t OF_BSUM = 0;
  constexpr size_t OF_LG   = OF_BSUM + 16384;
  constexpr size_t OF_H3A  = OF_LG   + 1048576;
  constexpr size_t OF_H3B  = OF_H3A  + 2097152;
  constexpr size_t OF_CUR3 = OF_H3B  + 2097152;
  constexpr size_t OF_P0A  = OF_CUR3 + 2097152;
  constexpr size_t OF_P0B  = OF_P0A  + 524288;
  constexpr size_t OF_CP0  = OF_P0B  + 524288;
  constexpr size_t OF_WIH  = OF_CP0  + 524288;
  constexpr size_t OF_WHH  = OF_WIH  + (size_t)3*NGATE*1024*2;
  constexpr size_t OF_WFC  = OF_WHH  + (size_t)3*NGATE*1024*2;
  constexpr size_t OF_INTS = OF_WFC  + (size_t)3*VOCAB*1024*2;

  float* bsum   = (float*)(W + OF_BSUM);
  float* logits = (float*)(W + OF_LG);
  ushort* h3a   = (ushort*)(W + OF_H3A);
  ushort* h3b   = (ushort*)(W + OF_H3B);
  ushort* cur3i = (ushort*)(W + OF_CUR3);
  ushort* h3p0a = (ushort*)(W + OF_P0A);
  ushort* h3p0b = (ushort*)(W + OF_P0B);
  ushort* curp0 = (ushort*)(W + OF_CP0);
  ushort* wih3  = (ushort*)(W + OF_WIH);
  ushort* whh3  = (ushort*)(W + OF_WHH);
  ushort* wfc3  = (ushort*)(W + OF_WFC);
  int* ints = (int*)(W + OF_INTS);

  splitw_kernel<<<NGATE/2, 256, 0, stream>>>(W_ih, wih3, NGATE);
  splitw_kernel<<<NGATE/2, 256, 0, stream>>>(W_hh, whh3, NGATE);
  splitw_kernel<<<VOCAB/2, 256, 0, stream>>>(W_fc, wfc3, VOCAB);
  prep_kernel<<<1024, 256, 0, stream>>>(b_ih, b_hh, x, lengths, bsum, ints,
                                        h3a, cur3i, h3p0a, curp0);

  KP P;
  P.x = x; P.W_ih = W_ih; P.b_fc = b_fc; P.bsum = bsum; P.lengths = lengths;
  P.logits = logits; P.out = out;
  P.h3a = h3a; P.h3b = h3b; P.cur3 = cur3i;
  P.wih3 = wih3; P.whh3 = whh3; P.wfc3 = wfc3;
  P.h3p0a = h3p0a; P.h3p0b = h3p0b; P.curp0 = curp0;
  P.ints = ints;
  P.guard = 0;

  persist<<<dim3(256), dim3(512), 0, stream>>>(P);
}

// Round 21
// 8878.542 us; speedup vs baseline: 1.2986x; 1.2986x over previous
//
#include <hip/hip_runtime.h>
#include <stdint.h>

#define HID 1024
#define NGATE 4096
#define BATCH 256
#define TENC 128
#define VOCAB 1024
#define NOUT 125
#define TDEC 141
#define MAXTHINK 16
#define STOPCLS 1023

typedef __attribute__((ext_vector_type(8))) short short8;
typedef __attribute__((ext_vector_type(4))) float f32x4;

#define WPLE ((size_t)NGATE*1024)
#define VPLE ((size_t)VOCAB*1024)
#define MFMA_B __builtin_amdgcn_mfma_f32_16x16x32_bf16

#define I_CLAIM 0
#define I_FLAGS 64
#define I_GEN   4224
#define I_ANY   4288
#define I_PRED  4608

// light barrier: waits LDS ops only, leaves global loads (vmcnt) in flight.
#define LBAR() do { asm volatile("s_waitcnt lgkmcnt(0)" ::: "memory"); \
                    __builtin_amdgcn_s_barrier(); } while(0)

// ---------------- threefry2x32 (exact JAX partitionable semantics) ----------------
__device__ __forceinline__ uint32_t rotl32(uint32_t v, int r){ return (v<<r)|(v>>(32-r)); }

__device__ __forceinline__ void tf2x32(uint32_t k0, uint32_t k1, uint32_t x0, uint32_t x1,
                                       uint32_t& o0, uint32_t& o1)
{
  uint32_t k2 = k0 ^ k1 ^ 0x1BD11BDAu;
  x0 += k0; x1 += k1;
#define R4(a,b,cc,d) x0+=x1;x1=rotl32(x1,a);x1^=x0; x0+=x1;x1=rotl32(x1,b);x1^=x0; \
                     x0+=x1;x1=rotl32(x1,cc);x1^=x0; x0+=x1;x1=rotl32(x1,d);x1^=x0;
  R4(13,15,26,6)  x0+=k1; x1+=k2+1u;
  R4(17,29,16,24) x0+=k2; x1+=k0+2u;
  R4(13,15,26,6)  x0+=k0; x1+=k1+3u;
  R4(17,29,16,24) x0+=k1; x1+=k2+4u;
  R4(13,15,26,6)  x0+=k2; x1+=k0+5u;
#undef R4
  o0 = x0; o1 = x1;
}

__device__ __forceinline__ uint32_t jax_bits(uint32_t fk0, uint32_t fk1, uint32_t i)
{
  uint32_t o0, o1;
  tf2x32(fk0, fk1, 0u, i, o0, o1);
  return o0 ^ o1;
}

__device__ __forceinline__ float sigm(float x){ return 0.5f + 0.5f*tanhf(0.5f*x); }

__device__ __forceinline__ ushort bf16rn(float v){
  uint32_t u = __float_as_uint(v);
  uint32_t r = (u + 0x7fffu + ((u>>16)&1u)) >> 16;
  return (ushort)r;
}
__device__ __forceinline__ float bf16tof(ushort s){ return __uint_as_float(((uint32_t)s)<<16); }

// ---------------- coherent (fabric) helpers: GLOBAL addrspace -> global_* (vmcnt only) ----
typedef unsigned long long __attribute__((address_space(1))) gu64_t;
typedef int                __attribute__((address_space(1))) gi32_t;
typedef unsigned short     __attribute__((address_space(1))) gu16_t;

__device__ __forceinline__ uint64_t cld8(const ushort* p){
  return __hip_atomic_load((const gu64_t*)(uintptr_t)p, __ATOMIC_RELAXED, __HIP_MEMORY_SCOPE_AGENT);
}
__device__ __forceinline__ void cst8(ushort* p, uint64_t v){
  __hip_atomic_store((gu64_t*)(uintptr_t)p, v, __ATOMIC_RELAXED, __HIP_MEMORY_SCOPE_AGENT);
}
__device__ __forceinline__ float cld4f(const float* p){
  int v = __hip_atomic_load((const gi32_t*)(uintptr_t)p, __ATOMIC_RELAXED, __HIP_MEMORY_SCOPE_AGENT);
  return __int_as_float(v);
}
__device__ __forceinline__ void cst4f(float* p, float x){
  __hip_atomic_store((gi32_t*)(uintptr_t)p, __float_as_int(x), __ATOMIC_RELAXED, __HIP_MEMORY_SCOPE_AGENT);
}
__device__ __forceinline__ int cld4i(const int* p){
  return __hip_atomic_load((const gi32_t*)(uintptr_t)p, __ATOMIC_RELAXED, __HIP_MEMORY_SCOPE_AGENT);
}
__device__ __forceinline__ void cst4i(int* p, int v){
  __hip_atomic_store((gi32_t*)(uintptr_t)p, v, __ATOMIC_RELAXED, __HIP_MEMORY_SCOPE_AGENT);
}
__device__ __forceinline__ ushort cld2(const ushort* p){
  return __hip_atomic_load((const gu16_t*)(uintptr_t)p, __ATOMIC_RELAXED, __HIP_MEMORY_SCOPE_AGENT);
}
__device__ __forceinline__ void cst2(ushort* p, ushort v){
  __hip_atomic_store((gu16_t*)(uintptr_t)p, v, __ATOMIC_RELAXED, __HIP_MEMORY_SCOPE_AGENT);
}

typedef ushort GatesLds[2][3][32][40];   // A staging: 32 rows x 32 elems, +pad
typedef ushort LdsXA[3][256][40];        // encoder x staging

// ---------------- grid barrier: pure control ----------------
__device__ __forceinline__ void gbar(int* flags, int* gen, int e, int rk, int tid)
{
  __syncthreads();     // drains vmcnt -> all coherent stores reached fabric
  if (tid == 0)
    __hip_atomic_store((gi32_t*)(uintptr_t)&flags[rk*16], e, __ATOMIC_RELAXED, __HIP_MEMORY_SCOPE_AGENT);
  if (rk == 0){
    if (tid < 256){
      while (cld4i(&flags[tid*16]) < e)
        __builtin_amdgcn_s_sleep(1);
    }
    __syncthreads();
    if (tid == 0)
      __hip_atomic_store((gi32_t*)(uintptr_t)gen, e, __ATOMIC_RELAXED, __HIP_MEMORY_SCOPE_AGENT);
  } else if (tid == 0){
    while (cld4i(gen) < e)
      __builtin_amdgcn_s_sleep(1);
  }
  __syncthreads();
}

// ---------------- prep ----------------
__global__ __launch_bounds__(256) void prep_kernel(
    const float* __restrict__ b_ih, const float* __restrict__ b_hh,
    const float* __restrict__ x, const int* __restrict__ lengths,
    float* __restrict__ bsum, int* __restrict__ ints,
    ushort* __restrict__ h3i, ushort* __restrict__ cur3i,
    ushort* __restrict__ h3p0, ushort* __restrict__ curp0)
{
  int idx = blockIdx.x*256 + threadIdx.x;           // b*1024 + k
  if (idx < NGATE) bsum[idx] = b_ih[idx] + b_hh[idx];
  if (idx < 8)   ints[I_CLAIM + idx] = 0;
  if (idx < 256) ints[I_FLAGS + idx*16] = 0;
  if (idx == 0)  ints[I_GEN] = 0;
  if (idx < TDEC+1) ints[I_ANY + idx] = (idx==0) ? 1 : 0;
  *(unsigned long long*)(h3i + (size_t)idx*4) = 0ull;
  h3p0[idx] = 0;
  int b = idx >> 10, k = idx & (HID-1);
  int L = lengths[b];
  float v = x[((size_t)b*TENC + (size_t)(L-1))*HID + k];
  ushort p0 = bf16rn(v); v -= bf16tof(p0);
  ushort p1 = bf16rn(v); v -= bf16tof(p1);
  ushort p2 = bf16rn(v);
  *(unsigned long long*)(cur3i + (size_t)idx*4) =
      (uint64_t)p0 | ((uint64_t)p1<<16) | ((uint64_t)p2<<32);
  curp0[idx] = p0;
}

// ---------------- weight pre-split into frag-ordered bf16 planes ----------------
__global__ __launch_bounds__(256) void splitw_kernel(
    const float* __restrict__ W, ushort* __restrict__ Wf, int N)
{
  int idx = blockIdx.x*256 + threadIdx.x;   // n*128 + kc
  int n = idx >> 7, kc = idx & 127;
  float v[8];
  *(float4*)&v[0] = *(const float4*)(W + (size_t)n*1024 + kc*8);
  *(float4*)&v[4] = *(const float4*)(W + (size_t)n*1024 + kc*8 + 4);
  size_t base = ((size_t)(n>>4)*128 + kc)*128 + (n&15)*8;
  #pragma unroll
  for (int p=0;p<3;p++){
    ushort o[8];
    #pragma unroll
    for (int e=0;e<8;e++){ ushort pp = bf16rn(v[e]); v[e] -= bf16tof(pp); o[e] = pp; }
    *(uint4*)(Wf + (size_t)p*N*1024 + base) = *(uint4*)o;
  }
}

// ================= phase helpers =================

// encoder chunk x-GEMM: block (tt,g) -> xg rows tt*256+[0,256) x cols g*128+[0,128)
__device__ void xgemm_do(const float* __restrict__ x, const ushort* __restrict__ wih,
                         float* __restrict__ xg_x, int tc, int xcc, int rank,
                         char* xa_mem, int tid)
{
  LdsXA& xa = *reinterpret_cast<LdsXA*>(xa_mem);
  int lane = tid & 63, w = tid >> 6;
  int fr = lane & 15, q = lane >> 4;
  int tt = rank >> 2, g = rank & 3;
  int srow = tid >> 1, half = (tid & 1) * 16;
  const float* xrow = x + ((size_t)srow*TENC + (tc*8 + tt))*HID;
  size_t off = ((size_t)(g*64 + xcc*8 + w)*128 + q)*128 + fr*8;

#define LOADX(dst, kc) { \
  int kcl = ((kc) < 32) ? (kc) : 0; \
  _Pragma("unroll") for (int i=0;i<4;i++) \
    *(float4*)&dst[i*4] = *(const float4*)(xrow + kcl*32 + half + i*4); }

#define SPLITSTORE(xv) { \
  _Pragma("unroll") for (int p=0;p<3;p++){ \
    ushort o[16]; \
    _Pragma("unroll") for (int e=0;e<16;e++){ ushort pp = bf16rn(xv[e]); xv[e] -= bf16tof(pp); o[e] = pp; } \
    *(uint4*)&xa[p][srow][half]   = *(uint4*)&o[0]; \
    *(uint4*)&xa[p][srow][half+8] = *(uint4*)&o[8]; } }

#define XLOADB(dst, kc) { \
  int kcl = ((kc) < 32) ? (kc) : 0; \
  _Pragma("unroll") for (int p=0;p<3;p++) \
    dst[p] = *(const short8*)(wih + (size_t)p*WPLE + off + (size_t)kcl*512); }

#define XMFMA(bq) { \
  _Pragma("unroll") for (int mf=0; mf<16; mf++){ \
    short8 af[3]; \
    _Pragma("unroll") for (int p=0;p<3;p++) af[p] = *(const short8*)&xa[p][mf*16+fr][q*8]; \
    acc[mf] = MFMA_B(af[2], bq[0], acc[mf], 0,0,0); \
    acc[mf] = MFMA_B(af[1], bq[1], acc[mf], 0,0,0); \
    acc[mf] = MFMA_B(af[0], bq[2], acc[mf], 0,0,0); \
    acc[mf] = MFMA_B(af[1], bq[0], acc[mf], 0,0,0); \
    acc[mf] = MFMA_B(af[0], bq[1], acc[mf], 0,0,0); \
    acc[mf] = MFMA_B(af[0], bq[0], acc[mf], 0,0,0); } }

  f32x4 acc[16] = {};
  float xv0[16], xv1[16];
  short8 bq0[3], bq1[3];
  LOADX(xv0, 0); XLOADB(bq0, 0);
  for (int kc = 0; kc < 32; kc += 2){
    LBAR();
    SPLITSTORE(xv0);
    LBAR();
    LOADX(xv1, kc+1); XLOADB(bq1, kc+1);
    XMFMA(bq0);
    LBAR();
    SPLITSTORE(xv1);
    LBAR();
    LOADX(xv0, kc+2); XLOADB(bq0, kc+2);
    XMFMA(bq1);
  }
#undef LOADX
#undef SPLITSTORE
#undef XLOADB
#undef XMFMA
  #pragma unroll
  for (int mf=0; mf<16; mf++)
    #pragma unroll
    for (int r=0;r<4;r++)
      cst4f(xg_x + (size_t)(tt*256 + mf*16 + q*4 + r)*512 + g*128 + w*16 + fr, acc[mf][r]);
}

// gates + LSTM cell. PL3: interleaved A records; PL1: compact plane-0 A (4x fewer bytes).
template<int PL, int MODE>
__device__ void gates_do(
    const ushort* __restrict__ A0i, const ushort* __restrict__ A1i,
    const ushort* __restrict__ A0c, const ushort* __restrict__ A1c,
    const ushort* __restrict__ Wih, const ushort* __restrict__ Whh,
    const float* __restrict__ Wihf, const int* __restrict__ pred,
    const float* __restrict__ xg_x,
    int t, const int* len2, const float (*bs2)[4],
    float* creg, ushort* __restrict__ h3newi, ushort* __restrict__ h3p0new,
    GatesLds& As, char* ep_mem,
    int xcc, int bb, int kg, int tid)
{
  constexpr int KT = (MODE==1) ? 64 : 32;
  float (*ep)[32][33] = reinterpret_cast<float(*)[32][33]>(ep_mem);
  int lane = tid & 63, w = tid >> 6;
  int fr = lane & 15, q = lane >> 4;
  int arow = tid >> 4, apos = tid & 15;
  int bf = w & 1, kf = (w>>1) & 1, gh = w >> 2;

  size_t off[2];
  #pragma unroll
  for (int g2=0; g2<2; g2++)
    off[g2] = ((size_t)((2*gh+g2)*64 + xcc*8 + kg*2 + kf)*128 + q)*128 + fr*8;

  f32x4 acc[2] = {};

#define LOADSA(sv, kc) { \
  int kcl = ((kc) < KT) ? (kc) : 0; \
  int kl = kcl & 31; \
  if constexpr (PL==3){ \
    const ushort* ai = (MODE==1 && kcl < 32) ? A0i : A1i; \
    _Pragma("unroll") for (int j=0;j<2;j++) \
      sv[j] = cld8(ai + ((size_t)(bb + arow)*1024 + kl*32 + apos*2 + j)*4); \
  } else { \
    const ushort* ac = (MODE==1 && kcl < 32) ? A0c : A1c; \
    sv[0] = (uint64_t)(uint)cld4i((const int*)(ac + (size_t)(bb + arow)*1024 + kl*32 + apos*2)); \
  } }

#define STAGE(buf, sv) { \
  if constexpr (PL==3){ \
    _Pragma("unroll") for (int p=0;p<3;p++){ \
      uint lo = (uint)((sv[0] >> (16*p)) & 0xffffu) | ((uint)((sv[1] >> (16*p)) & 0xffffu) << 16); \
      *(uint*)&As[buf][p][arow][apos*2] = lo; } \
  } else { \
    *(uint*)&As[buf][0][arow][apos*2] = (uint)sv[0]; \
  } }

#define LOADB(dst, kc) { \
  int kcl = ((kc) < KT) ? (kc) : 0; \
  const ushort* wsel = (MODE==1 && kcl < 32) ? Wih : Whh; \
  int kl = kcl & 31; \
  _Pragma("unroll") for (int p=0;p<PL;p++) \
  _Pragma("unroll") for (int g2=0; g2<2; g2++) \
    dst[p][g2] = *(const short8*)(wsel + (size_t)p*WPLE + off[g2] + (size_t)kl*512); }

#define READA(af, buf) { _Pragma("unroll") for (int p=0;p<PL;p++) af[p] = *(const short8*)&As[buf][p][bf*16 + fr][q*8]; }

#define DOMFMA(aa, bf_) { _Pragma("unroll") for (int g2=0; g2<2; g2++){ \
  if constexpr (PL==3){ \
    acc[g2] = MFMA_B(aa[2], bf_[0][g2], acc[g2], 0,0,0); \
    acc[g2] = MFMA_B(aa[1], bf_[1][g2], acc[g2], 0,0,0); \
    acc[g2] = MFMA_B(aa[0], bf_[2][g2], acc[g2], 0,0,0); \
    acc[g2] = MFMA_B(aa[1], bf_[0][g2], acc[g2], 0,0,0); \
    acc[g2] = MFMA_B(aa[0], bf_[1][g2], acc[g2], 0,0,0); \
    acc[g2] = MFMA_B(aa[0], bf_[0][g2], acc[g2], 0,0,0); \
  } else { \
    acc[g2] = MFMA_B(aa[0], bf_[0][g2], acc[g2], 0,0,0); \
  } } }

  uint64_t sv0[2], sv1[2], sv2[2], sv3[2];
  short8 bq0[PL][2], bq1[PL][2], afc[PL], afn[PL];
  LOADSA(sv0, 0); LOADSA(sv1, 1); LOADSA(sv2, 2); LOADSA(sv3, 3);
  LOADB(bq0, 0);
  STAGE(0, sv0); LBAR();
  READA(afc, 0);
  LOADSA(sv0, 4);
  for (int kc = 0; kc < KT; kc += 4){
    STAGE(1, sv1); LBAR();
    READA(afn, 1);
    LOADB(bq1, kc+1); LOADSA(sv1, kc+5);
    DOMFMA(afc, bq0);

    STAGE(0, sv2); LBAR();
    READA(afc, 0);
    LOADB(bq0, kc+2); LOADSA(sv2, kc+6);
    DOMFMA(afn, bq1);

    STAGE(1, sv3); LBAR();
    READA(afn, 1);
    LOADB(bq1, kc+3); LOADSA(sv3, kc+7);
    DOMFMA(afc, bq0);

    STAGE(0, sv0); LBAR();
    READA(afc, 0);
    LOADB(bq0, kc+4); LOADSA(sv0, kc+8);
    DOMFMA(afn, bq1);
  }
#undef LOADSA
#undef STAGE
#undef LOADB
#undef READA
#undef DOMFMA

  // exchange accumulators through LDS, then per-element cell epilogue
  __syncthreads();
  #pragma unroll
  for (int g2=0; g2<2; g2++)
    #pragma unroll
    for (int r=0;r<4;r++)
      ep[2*gh+g2][bf*16 + q*4 + r][kf*16 + fr] = acc[g2][r];
  __syncthreads();

  #pragma unroll
  for (int e2=0; e2<2; e2++){
    int e = tid + e2*512;
    int b_loc = e >> 5, k_loc = e & 31;
    int b = bb + b_loc;
    int kkloc = kg*32 + k_loc;
    int kkg = xcc*128 + kkloc;
    size_t eidx = (size_t)b*1024 + kkg;
    if (MODE==0 && t >= len2[e2]){
      cst8(h3newi + eidx*4, cld8(A1i + eidx*4));   // keep old h (c untouched)
      cst2(h3p0new + eidx, cld2(A1c + eidx));
      continue;
    }
    float gi = ep[0][b_loc][k_loc], gf = ep[1][b_loc][k_loc];
    float gg2v = ep[2][b_loc][k_loc], go = ep[3][b_loc][k_loc];
    if (MODE==0){
      const float* xr = xg_x + (size_t)((t&7)*256 + b)*512;
      gi   += cld4f(xr + kkloc);
      gf   += cld4f(xr + 128 + kkloc);
      gg2v += cld4f(xr + 256 + kkloc);
      go   += cld4f(xr + 384 + kkloc);
    }
    if (MODE==2){
      int pp = cld4i(pred + b);
      gi   += Wihf[(size_t)(        kkg)*1024 + pp];
      gf   += Wihf[(size_t)(1024 + kkg)*1024 + pp];
      gg2v += Wihf[(size_t)(2048 + kkg)*1024 + pp];
      go   += Wihf[(size_t)(3072 + kkg)*1024 + pp];
    }
    gi += bs2[e2][0]; gf += bs2[e2][1]; gg2v += bs2[e2][2]; go += bs2[e2][3];
    float cn = sigm(gf)*creg[e2] + sigm(gi)*tanhf(gg2v);
    float hn = sigm(go)*tanhf(cn);
    creg[e2] = cn;
    float v = hn;
    ushort p0 = bf16rn(v); v -= bf16tof(p0);
    cst2(h3p0new + eidx, p0);
    if constexpr (PL==3){
      ushort p1 = bf16rn(v); v -= bf16tof(p1);
      ushort p2 = bf16rn(v);
      cst8(h3newi + eidx*4, (uint64_t)p0 | ((uint64_t)p1<<16) | ((uint64_t)p2<<32));
    }
  }
}

// FC: PL3 reads interleaved h3i; PL1 reads compact h3c plane-0.
template<int PL>
__device__ void fc_do(
    const ushort* __restrict__ h3i, const ushort* __restrict__ h3c,
    const ushort* __restrict__ wfc,
    float* __restrict__ logits, GatesLds& As,
    int xcc, int bb, int vg, int tid)
{
  int lane = tid & 63, w = tid >> 6;
  int fr = lane & 15, q = lane >> 4;
  int arow = tid >> 4, apos = tid & 15;
  int bf = w & 1, vf = (w>>1) & 1;
  bool act = (w < 4);
  size_t off = ((size_t)(xcc*8 + vg*2 + vf)*128 + q)*128 + fr*8;
  f32x4 acc = {};

#define FLOADSA(sv, kc) { \
  int kcl = ((kc) < 32) ? (kc) : 0; \
  if constexpr (PL==3){ \
    _Pragma("unroll") for (int j=0;j<2;j++) \
      sv[j] = cld8(h3i + ((size_t)(bb + arow)*1024 + kcl*32 + apos*2 + j)*4); \
  } else { \
    sv[0] = (uint64_t)(uint)cld4i((const int*)(h3c + (size_t)(bb + arow)*1024 + kcl*32 + apos*2)); \
  } }

#define FSTAGE(buf, sv) { \
  if constexpr (PL==3){ \
    _Pragma("unroll") for (int p=0;p<3;p++){ \
      uint lo = (uint)((sv[0] >> (16*p)) & 0xffffu) | ((uint)((sv[1] >> (16*p)) & 0xffffu) << 16); \
      *(uint*)&As[buf][p][arow][apos*2] = lo; } \
  } else { \
    *(uint*)&As[buf][0][arow][apos*2] = (uint)sv[0]; \
  } }

#define FLOADB(dst, kc) { if (act){ \
  int kcl = ((kc) < 32) ? (kc) : 0; \
  _Pragma("unroll") for (int p=0;p<PL;p++) \
    dst[p] = *(const short8*)(wfc + (size_t)p*VPLE + off + (size_t)kcl*512); } }

#define FMM(aa, bf_) { if (act){ \
  if constexpr (PL==3){ \
    acc = MFMA_B(aa[2], bf_[0], acc, 0,0,0); \
    acc = MFMA_B(aa[1], bf_[1], acc, 0,0,0); \
    acc = MFMA_B(aa[0], bf_[2], acc, 0,0,0); \
    acc = MFMA_B(aa[1], bf_[0], acc, 0,0,0); \
    acc = MFMA_B(aa[0], bf_[1], acc, 0,0,0); \
    acc = MFMA_B(aa[0], bf_[0], acc, 0,0,0); \
  } else { \
    acc = MFMA_B(aa[0], bf_[0], acc, 0,0,0); \
  } } }

#define FREADA(af, buf) { if (act){ _Pragma("unroll") for (int p=0;p<PL;p++) af[p] = *(const short8*)&As[buf][p][bf*16 + fr][q*8]; } }

  uint64_t sv0[2], sv1[2], sv2[2], sv3[2];
  short8 bq0[PL], bq1[PL], afc[PL], afn[PL];
  FLOADSA(sv0, 0); FLOADSA(sv1, 1); FLOADSA(sv2, 2); FLOADSA(sv3, 3);
  FLOADB(bq0, 0);
  FSTAGE(0, sv0); LBAR();
  FREADA(afc, 0);
  FLOADSA(sv0, 4);
  for (int kc = 0; kc < 32; kc += 4){
    FSTAGE(1, sv1); LBAR();
    FREADA(afn, 1);
    FLOADB(bq1, kc+1); FLOADSA(sv1, kc+5);
    FMM(afc, bq0);

    FSTAGE(0, sv2); LBAR();
    FREADA(afc, 0);
    FLOADB(bq0, kc+2); FLOADSA(sv2, kc+6);
    FMM(afn, bq1);

    FSTAGE(1, sv3); LBAR();
    FREADA(afn, 1);
    FLOADB(bq1, kc+3); FLOADSA(sv3, kc+7);
    FMM(afc, bq0);

    FSTAGE(0, sv0); LBAR();
    FREADA(afc, 0);
    FLOADB(bq0, kc+4); FLOADSA(sv0, kc+8);
    FMM(afn, bq1);
  }
#undef FLOADSA
#undef FSTAGE
#undef FLOADB
#undef FMM
#undef FREADA

  if (act){
    int v = xcc*128 + vg*32 + vf*16 + fr;
    #pragma unroll
    for (int r=0;r<4;r++)
      cst4f(logits + (size_t)(bb + bf*16 + q*4 + r)*1024 + v, acc[r]);
  }
}

// decide: one block per batch b (512 threads, 2 vocab each); state in registers
__device__ void decide_do(
    const float* __restrict__ logits, const float* __restrict__ b_fc, int t, int b,
    int* anyA, int* pred, float* __restrict__ out,
    ushort* __restrict__ cur3i, ushort* __restrict__ curp0,
    int& isth, int& tsteps, int& osteps,
    float* s_red, int* s_idx, int* s_misc, int tid)
{
  if (tid==0) s_misc[0] = cld4i(anyA + t);
  uint32_t fk0, fk1; tf2x32(0u, 42u, 0u, (uint32_t)t, fk0, fk1);
  float lg[2];
  float zb = -3.4e38f; int ib = 0;
  #pragma unroll
  for (int q2=0;q2<2;q2++){
    int v = tid + (q2<<9);
    uint32_t bits = jax_bits(fk0, fk1, (uint32_t)(b*VOCAB + v));
    float f = __uint_as_float((bits>>9) | 0x3F800000u) - 1.0f;
    const float TINY = 1.17549435e-38f;
    float u = fmaxf(TINY, f + TINY);
    float g = -logf(-logf(u));
    float l = cld4f(logits + (size_t)b*VOCAB + v) + b_fc[v];
    lg[q2] = l;
    float zz = l + g;
    if (zz > zb){ zb = zz; ib = v; }
  }
  s_red[tid] = zb; s_idx[tid] = ib;
  __syncthreads();
  for (int s2=256;s2>0;s2>>=1){
    if (tid < s2){
      float om = s_red[tid+s2]; int oi = s_idx[tid+s2];
      if (om > s_red[tid] || (om==s_red[tid] && oi < s_idx[tid])){ s_red[tid]=om; s_idx[tid]=oi; }
    }
    __syncthreads();
  }
  int predv = s_idx[0];
  int anyv  = s_misc[0];
  int outp = (!isth && osteps < NOUT) ? 1 : 0;
  int si = osteps < (NOUT-1) ? osteps : (NOUT-1);
  int nts = tsteps + (isth ? 1 : 0);
  int jf = (isth && ((predv==STOPCLS) || (nts >= MAXTHINK))) ? 1 : 0;
  int isnew = (isth && !jf) ? 1 : 0;
  if (tid==0){
    cst4i(pred + b, predv);
    if (isnew) __hip_atomic_fetch_or(&anyA[t+1], 1, __ATOMIC_RELAXED, __HIP_MEMORY_SCOPE_AGENT);
    if (t == TDEC-1) out[(size_t)BATCH*NOUT*(VOCAB-1) + b] = (float)nts;
  }
  osteps += outp; tsteps = nts; isth = isnew;
  #pragma unroll
  for (int q2=0;q2<2;q2++){
    int v = tid + (q2<<9);
    float l = lg[q2];
    float cv = anyv ? l : (v==predv ? 1.0f : 0.0f);
    if (t < MAXTHINK){
      float t2 = cv;
      ushort p0 = bf16rn(t2); t2 -= bf16tof(p0);
      ushort p1 = bf16rn(t2); t2 -= bf16tof(p1);
      ushort p2 = bf16rn(t2);
      cst8(cur3i + ((size_t)b*1024 + v)*4,
           (uint64_t)p0 | ((uint64_t)p1<<16) | ((uint64_t)p2<<32));
      cst2(curp0 + (size_t)b*1024 + v, p0);
    }
    if (outp && v < (VOCAB-1))
      out[((size_t)b*NOUT + si)*(VOCAB-1) + v] = l;
  }
}

// ================= persistent kernel =================
struct KP {
  const float *x, *W_ih, *b_fc, *bsum;
  const int *lengths;
  float *logits, *out, *xg;
  ushort *h3a, *h3b, *cur3, *wih3, *whh3, *wfc3;
  ushort *h3p0a, *h3p0b, *curp0;
  int *ints;
  int guard;
};

__global__ __launch_bounds__(512, 2) void persist(KP P)
{
  __shared__ __align__(16) char xa_mem[61440];   // xgemm staging / gates epilogue exchange
  __shared__ __align__(16) GatesLds As;          // 15360 B
  __shared__ float s_red[512];
  __shared__ int s_idx[512];
  __shared__ int s_misc[16];
  __shared__ char lds_pad[8192];                 // total > 80 KiB -> 1 block/CU
  if (P.guard) ((volatile char*)lds_pad)[0] = 1;

  int tid = threadIdx.x;
  int xcc; asm("s_getreg_b32 %0, hwreg(HW_REG_XCC_ID)" : "=s"(xcc));
  xcc &= 7;
  if (tid == 0)
    s_misc[8] = __hip_atomic_fetch_add(&P.ints[I_CLAIM + xcc], 1, __ATOMIC_RELAXED, __HIP_MEMORY_SCOPE_AGENT);
  __syncthreads();
  int rank  = s_misc[8] & 31;                 // 32 blocks/XCD by 1-block/CU residency
  int rk256 = xcc*32 + rank;

  int bg = rank >> 2, kg = rank & 3;
  int bb = bg * 32;

  float bs2[2][4]; int len2[2]; float creg[2] = {0.f, 0.f};
  #pragma unroll
  for (int e2=0; e2<2; e2++){
    int e = tid + e2*512;
    int b_loc = e >> 5, k_loc = e & 31;
    int b = bb + b_loc;
    int kkg = xcc*128 + kg*32 + k_loc;
    #pragma unroll
    for (int g=0; g<4; g++) bs2[e2][g] = P.bsum[g*1024 + kkg];
    len2[e2] = P.lengths[b];
  }

  int* flags = P.ints + I_FLAGS;
  int* gen   = P.ints + I_GEN;
  int* anyA  = P.ints + I_ANY;
  int* pred  = P.ints + I_PRED;
  int epoch = 0;
  ushort* h3[2]   = { P.h3a,   P.h3b };
  ushort* h3p0[2] = { P.h3p0a, P.h3p0b };
  int hc = 0;
  int isth = 1, tsteps = 0, osteps = 0;
  float* xg_x = P.xg + (size_t)xcc*2048*512;

#define GBAR() gbar(flags, gen, ++epoch, rk256, tid)

  // ---- encoder: 16 chunks x { xgemm , 8 gate steps } ----
  for (int tc = 0; tc < TENC/8; ++tc){
    xgemm_do(P.x, P.wih3, xg_x, tc, xcc, rank, xa_mem, tid);
    GBAR();
    for (int tt = 0; tt < 8; ++tt){
      int t = tc*8 + tt;
      gates_do<3,0>(nullptr, h3[hc], nullptr, h3p0[hc], nullptr, P.whh3, nullptr, nullptr, xg_x,
                    t, len2, bs2, creg, h3[hc^1], h3p0[hc^1], As, xa_mem, xcc, bb, kg, tid);
      hc ^= 1;
      GBAR();
    }
  }

  // ---- decode: 141 steps x { gates, fc, decide } ----
  for (int t = 0; t < TDEC; ++t){
    if (t < MAXTHINK)
      gates_do<3,1>(P.cur3, h3[hc], nullptr, nullptr, P.wih3, P.whh3, nullptr, nullptr, nullptr,
                    t, len2, bs2, creg, h3[hc^1], h3p0[hc^1], As, xa_mem, xcc, bb, kg, tid);
    else if (t == MAXTHINK)   // cur entering t=16 is LOGITS (any was true at t=15)
      gates_do<1,1>(nullptr, nullptr, P.curp0, h3p0[hc], P.wih3, P.whh3, nullptr, nullptr, nullptr,
                    t, len2, bs2, creg, h3[hc^1], h3p0[hc^1], As, xa_mem, xcc, bb, kg, tid);
    else                      // t>=17: cur exactly one-hot -> W_ih column gather
      gates_do<1,2>(nullptr, nullptr, nullptr, h3p0[hc], nullptr, P.whh3, P.W_ih, pred, nullptr,
                    t, len2, bs2, creg, h3[hc^1], h3p0[hc^1], As, xa_mem, xcc, bb, kg, tid);
    hc ^= 1;
    GBAR();
    if (t < MAXTHINK) fc_do<3>(h3[hc], nullptr, P.wfc3, P.logits, As, xcc, bb, kg, tid);
    else              fc_do<1>(nullptr, h3p0[hc], P.wfc3, P.logits, As, xcc, bb, kg, tid);
    GBAR();
    decide_do(P.logits, P.b_fc, t, rk256, anyA, pred, P.out, P.cur3, P.curp0,
              isth, tsteps, osteps, s_red, s_idx, s_misc, tid);
    GBAR();
  }
#undef GBAR
}

// ---------------- host ----------------
extern "C" void kernel_launch(void* const* d_in, const int* in_sizes, int n_in,
                              void* d_out, int out_size, void* d_ws, size_t ws_size,
                              hipStream_t stream)
{
  const float* x    = (const float*)d_in[0];
  const float* W_ih = (const float*)d_in[1];
  const float* W_hh = (const float*)d_in[2];
  const float* b_ih = (const float*)d_in[3];
  const float* b_hh = (const float*)d_in[4];
  const float* W_fc = (const float*)d_in[5];
  const float* b_fc = (const float*)d_in[6];
  const int*   lengths = (const int*)d_in[7];
  float* out = (float*)d_out;
  char* W = (char*)d_ws;

  constexpr size_t OF_BSUM = 0;
  constexpr size_t OF_LG   = OF_BSUM + 16384;
  constexpr size_t OF_H3A  = OF_LG   + 1048576;
  constexpr size_t OF_H3B  = OF_H3A  + 2097152;
  constexpr size_t OF_CUR3 = OF_H3B  + 2097152;
  constexpr size_t OF_P0A  = OF_CUR3 + 2097152;
  constexpr size_t OF_P0B  = OF_P0A  + 524288;
  constexpr size_t OF_CP0  = OF_P0B  + 524288;
  constexpr size_t OF_WIH  = OF_CP0  + 524288;
  constexpr size_t OF_WHH  = OF_WIH  + (size_t)3*NGATE*1024*2;
  constexpr size_t OF_WFC  = OF_WHH  + (size_t)3*NGATE*1024*2;
  constexpr size_t OF_INTS = OF_WFC  + (size_t)3*VOCAB*1024*2;

  float* bsum   = (float*)(W + OF_BSUM);
  float* logits = (float*)(W + OF_LG);
  ushort* h3a   = (ushort*)(W + OF_H3A);
  ushort* h3b   = (ushort*)(W + OF_H3B);
  ushort* cur3i = (ushort*)(W + OF_CUR3);
  ushort* h3p0a = (ushort*)(W + OF_P0A);
  ushort* h3p0b = (ushort*)(W + OF_P0B);
  ushort* curp0 = (ushort*)(W + OF_CP0);
  ushort* wih3  = (ushort*)(W + OF_WIH);
  ushort* whh3  = (ushort*)(W + OF_WHH);
  ushort* wfc3  = (ushort*)(W + OF_WFC);
  int* ints = (int*)(W + OF_INTS);

  // encoder-only scratch aliased into d_out's fo region (fully rewritten in out-phase);
  // accessed only via coherent atomics so no dirty-L2 clobber of later fo writes.
  float* xg = (float*)d_out;   // 8 XCD x 2048 rows x 512 cols f32 = 32 MiB

  splitw_kernel<<<NGATE/2, 256, 0, stream>>>(W_ih, wih3, NGATE);
  splitw_kernel<<<NGATE/2, 256, 0, stream>>>(W_hh, whh3, NGATE);
  splitw_kernel<<<VOCAB/2, 256, 0, stream>>>(W_fc, wfc3, VOCAB);
  prep_kernel<<<1024, 256, 0, stream>>>(b_ih, b_hh, x, lengths, bsum, ints,
                                        h3a, cur3i, h3p0a, curp0);

  KP P;
  P.x = x; P.W_ih = W_ih; P.b_fc = b_fc; P.bsum = bsum; P.lengths = lengths;
  P.logits = logits; P.out = out; P.xg = xg;
  P.h3a = h3a; P.h3b = h3b; P.cur3 = cur3i;
  P.wih3 = wih3; P.whh3 = whh3; P.wfc3 = wfc3;
  P.h3p0a = h3p0a; P.h3p0b = h3p0b; P.curp0 = curp0;
  P.ints = ints;
  P.guard = 0;

  persist<<<dim3(256), dim3(512), 0, stream>>>(P);
}